// Round 5
// baseline (214.010 us; speedup 1.0000x reference)
//
#include <hip/hip_runtime.h>
#include <hip/hip_bf16.h>
#include <math.h>

#define D_PET 128
#define NK    256
#define NB    2048
#define NBATCH 16

__device__ __forceinline__ float silu(float x) {
    return x / (1.0f + expf(-x));
}

__device__ __forceinline__ int lower_bound_dev(const int* a, int n, int v) {
    int lo = 0, hi = n;
    while (lo < hi) {
        int m = (lo + hi) >> 1;
        if (a[m] < v) lo = m + 1; else hi = m;
    }
    return lo;
}

// ---------------------------------------------------------------------------
// Kernel 1: pc[n][k] = (cos, sin) of phase(n,k).  grid = NB blocks, NK thr.
// ---------------------------------------------------------------------------
__global__ __launch_bounds__(NK) void phase_kernel(
        const float* __restrict__ kvec, const float* __restrict__ pos,
        const int* __restrict__ batch, float2* __restrict__ pc) {
    int n = blockIdx.x;
    int k = threadIdx.x;
    int b = batch[n];
    float p0 = pos[n * 3 + 0], p1 = pos[n * 3 + 1], p2 = pos[n * 3 + 2];
    const float* kv = kvec + ((size_t)b * NK + k) * 3;
    float ph = fmaf(p0, kv[0], fmaf(p1, kv[1], p2 * kv[2]));
    float s, c;
    sincosf(ph, &s, &c);
    pc[(size_t)n * NK + k] = make_float2(c, s);
}

// ---------------------------------------------------------------------------
// Kernel 2 (fused MLP + segment-sum), high-TLP version:
// SKT=4 k's per block -> 16*64 = 1024 blocks (16 waves/CU).
// thread: d = tid&127, kg = tid>>7 -> 2 k's (k0, k0+1).
// MLP for the 4 k-vecs computed in-block (redundant per block, but tiny);
// atom loop: per n, 1 coalesced b32 h load + 1 broadcast b128 pc load + 4 FMA,
// unrolled x4 -> 8 independent loads in flight, no barriers in the loop.
// ---------------------------------------------------------------------------
#define SKT 4
__global__ __launch_bounds__(256) void s_fused_kernel(
        const float* __restrict__ h, const float2* __restrict__ pc,
        const int* __restrict__ batch, const float* __restrict__ kvec,
        const float* __restrict__ W1, const float* __restrict__ b1,
        const float* __restrict__ W2, const float* __restrict__ b2,
        const float* __restrict__ W3, const float* __restrict__ b3,
        float2* __restrict__ t2) {
    int b  = blockIdx.x >> 6;          // / 64
    int kt = blockIdx.x & 63;
    int d  = threadIdx.x & (D_PET - 1);
    int kg = threadIdx.x >> 7;         // 0/1
    int bk0 = b * NK + kt * SKT;       // first flat k-vector index of block
    int k0  = kt * SKT + kg * 2;       // this thread's first k (even!)

    __shared__ float kv_s[SKT * 3];
    __shared__ float x_lds[D_PET * SKT];   // [e][j], 2 KB

    if (threadIdx.x < SKT * 3) kv_s[threadIdx.x] = kvec[bk0 * 3 + threadIdx.x];
    __syncthreads();

    // ---- layer 1: 3 -> 128, silu ----
    float w10 = W1[d], w11 = W1[D_PET + d], w12 = W1[2 * D_PET + d];
    float bb1 = b1[d];
    float2 x1;
    {
        float* xp = (float*)&x1;
#pragma unroll
        for (int i = 0; i < 2; i++) {
            int j = kg * 2 + i;
            float a = bb1;
            a = fmaf(kv_s[j * 3 + 0], w10, a);
            a = fmaf(kv_s[j * 3 + 1], w11, a);
            a = fmaf(kv_s[j * 3 + 2], w12, a);
            xp[i] = silu(a);
        }
    }
    *(float2*)&x_lds[(d << 2) + (kg << 1)] = x1;
    __syncthreads();

    // ---- layer 2: 128 -> 128, silu ----
    float a0 = b2[d], a1 = a0;
#pragma unroll 8
    for (int e = 0; e < D_PET; e++) {
        float w = W2[e * D_PET + d];
        float2 xv = *(const float2*)&x_lds[(e << 2) + (kg << 1)];  // broadcast
        a0 = fmaf(xv.x, w, a0);
        a1 = fmaf(xv.y, w, a1);
    }
    float2 x2 = make_float2(silu(a0), silu(a1));
    __syncthreads();
    *(float2*)&x_lds[(d << 2) + (kg << 1)] = x2;
    __syncthreads();

    // ---- layer 3: 128 -> 128 -> filt in registers ----
    float f0 = b3[d], f1 = f0;
#pragma unroll 8
    for (int e = 0; e < D_PET; e++) {
        float w = W3[e * D_PET + d];
        float2 xv = *(const float2*)&x_lds[(e << 2) + (kg << 1)];
        f0 = fmaf(xv.x, w, f0);
        f1 = fmaf(xv.y, w, f1);
    }

    // ---- segment sum over atoms of this batch ----
    int lo = lower_bound_dev(batch, NB, b);
    int hi = lower_bound_dev(batch, NB, b + 1);

    float sre0 = 0.f, sim0 = 0.f, sre1 = 0.f, sim1 = 0.f;

    int n = lo;
    for (; n + 3 < hi; n += 4) {
#pragma unroll
        for (int u = 0; u < 4; u++) {
            int nn = n + u;
            float hv = h[(size_t)nn * D_PET + d];
            float4 q = *(const float4*)(pc + (size_t)nn * NK + k0); // c0,s0,c1,s1
            sre0 = fmaf(q.x, hv, sre0); sim0 = fmaf(-q.y, hv, sim0);
            sre1 = fmaf(q.z, hv, sre1); sim1 = fmaf(-q.w, hv, sim1);
        }
    }
    for (; n < hi; n++) {
        float hv = h[(size_t)n * D_PET + d];
        float4 q = *(const float4*)(pc + (size_t)n * NK + k0);
        sre0 = fmaf(q.x, hv, sre0); sim0 = fmaf(-q.y, hv, sim0);
        sre1 = fmaf(q.z, hv, sre1); sim1 = fmaf(-q.w, hv, sim1);
    }

    size_t idx0 = ((size_t)b * NK + k0) * D_PET + d;
    t2[idx0]          = make_float2(sre0 * f0, sim0 * f0);
    t2[idx0 + D_PET]  = make_float2(sre1 * f1, sim1 * f1);
}

// ---------------------------------------------------------------------------
// Kernel 3: out[n,d] = sum_k e^{+i phi_nk} * t2[batch[n],k,d]
// Pure streaming, latency-first: 1 wave per (atom-pair, d-half) -> 2048 waves
// (512 blocks x 256 thr). NO LDS, NO barriers. Per k: 2 coalesced b64 t2
// loads (pair shares the row; 2nd hits L1 when batches match), 2 broadcast
// pc loads, 8 FMA. unroll 8 keeps ~32 loads in flight per wave.
// ---------------------------------------------------------------------------
__global__ __launch_bounds__(256) void out_kernel(
        const float2* __restrict__ pc, const int* __restrict__ batch,
        const float2* __restrict__ t2, float* __restrict__ out,
        int interleaved) {
    int w    = (blockIdx.x << 2) + (threadIdx.x >> 6);   // 0..2047
    int lane = threadIdx.x & 63;
    int p    = w >> 1;            // atom pair 0..1023
    int dh   = w & 1;             // d half
    int n0   = p * 2, n1 = n0 + 1;
    int d    = dh * 64 + lane;

    int b0 = batch[n0], b1 = batch[n1];
    const float2* tr0 = t2 + (size_t)b0 * NK * D_PET + d;
    const float2* tr1 = t2 + (size_t)b1 * NK * D_PET + d;
    const float2* p0  = pc + (size_t)n0 * NK;
    const float2* p1  = pc + (size_t)n1 * NK;

    float ore0 = 0.f, oim0 = 0.f, ore1 = 0.f, oim1 = 0.f;

#pragma unroll 8
    for (int k = 0; k < NK; k++) {
        float2 tv0 = tr0[(size_t)k * D_PET];
        float2 tv1 = tr1[(size_t)k * D_PET];
        float2 c0  = p0[k];    // broadcast
        float2 c1  = p1[k];    // broadcast
        ore0 = fmaf(c0.x, tv0.x, ore0); ore0 = fmaf(-c0.y, tv0.y, ore0);
        oim0 = fmaf(c0.x, tv0.y, oim0); oim0 = fmaf(c0.y, tv0.x, oim0);
        ore1 = fmaf(c1.x, tv1.x, ore1); ore1 = fmaf(-c1.y, tv1.y, ore1);
        oim1 = fmaf(c1.x, tv1.y, oim1); oim1 = fmaf(c1.y, tv1.x, oim1);
    }

    if (interleaved) {
        float2* o2 = (float2*)out;
        o2[(size_t)n0 * D_PET + d] = make_float2(ore0, oim0);
        o2[(size_t)n1 * D_PET + d] = make_float2(ore1, oim1);
    } else {
        out[(size_t)n0 * D_PET + d] = ore0;
        out[(size_t)n1 * D_PET + d] = ore1;
    }
}

// ---------------------------------------------------------------------------
extern "C" void kernel_launch(void* const* d_in, const int* in_sizes, int n_in,
                              void* d_out, int out_size, void* d_ws, size_t ws_size,
                              hipStream_t stream) {
    const float* kvec = (const float*)d_in[0];   // [16,256,3]
    const float* pos  = (const float*)d_in[1];   // [2048,3]
    const float* h    = (const float*)d_in[2];   // [2048,128]
    const float* W1   = (const float*)d_in[3];
    const float* b1   = (const float*)d_in[4];
    const float* W2   = (const float*)d_in[5];
    const float* b2   = (const float*)d_in[6];
    const float* W3   = (const float*)d_in[7];
    const float* b3   = (const float*)d_in[8];
    const int*   batch = (const int*)d_in[9];    // [2048]

    float2* pc = (float2*)d_ws;                              // [NB][NK]    4 MB
    float2* t2 = pc + (size_t)NB * NK;                       // [B][NK][D]  4 MB

    int interleaved = (out_size == NB * D_PET * 2) ? 1 : 0;

    phase_kernel<<<NB, NK, 0, stream>>>(kvec, pos, batch, pc);
    s_fused_kernel<<<NBATCH * (NK / SKT), 256, 0, stream>>>(h, pc, batch, kvec,
                                                    W1, b1, W2, b2, W3, b3, t2);
    out_kernel<<<NB / 4, 256, 0, stream>>>(pc, batch, t2,
                                           (float*)d_out, interleaved);
}

// Round 7
// 191.199 us; speedup vs baseline: 1.1193x; 1.1193x over previous
//
#include <hip/hip_runtime.h>
#include <hip/hip_bf16.h>
#include <math.h>

#define D_PET 128
#define NK    256
#define NB    2048
#define NBATCH 16

__device__ __forceinline__ float silu(float x) {
    return x / (1.0f + expf(-x));
}

__device__ __forceinline__ int lower_bound_dev(const int* a, int n, int v) {
    int lo = 0, hi = n;
    while (lo < hi) {
        int m = (lo + hi) >> 1;
        if (a[m] < v) lo = m + 1; else hi = m;
    }
    return lo;
}

// ---------------------------------------------------------------------------
// Kernel 1: pc[n][k] = (cos, sin) of phase(n,k).  grid = NB blocks, NK thr.
// ---------------------------------------------------------------------------
__global__ __launch_bounds__(NK) void phase_kernel(
        const float* __restrict__ kvec, const float* __restrict__ pos,
        const int* __restrict__ batch, float2* __restrict__ pc) {
    int n = blockIdx.x;
    int k = threadIdx.x;
    int b = batch[n];
    float p0 = pos[n * 3 + 0], p1 = pos[n * 3 + 1], p2 = pos[n * 3 + 2];
    const float* kv = kvec + ((size_t)b * NK + k) * 3;
    float ph = fmaf(p0, kv[0], fmaf(p1, kv[1], p2 * kv[2]));
    float s, c;
    sincosf(ph, &s, &c);
    pc[(size_t)n * NK + k] = make_float2(c, s);
}

// ---------------------------------------------------------------------------
// Kernel 2: fused MLP + segment-sum GEMM.
// Block = (batch b, 16-k tile). 256 blocks, 256 threads.
// thread: d = tid&127, kg = tid>>7 -> 8 k's => 16 accumulators.
// Segment part tiles atoms by 32: h-tile (16KB) + e-tile (4KB) staged in LDS,
// inner loop = 16 FMA + 5 LDS reads per atom => latency amortized.
// ---------------------------------------------------------------------------
#define SKB 16
__global__ __launch_bounds__(256) void s_fused_kernel(
        const float* __restrict__ h, const float2* __restrict__ pc,
        const int* __restrict__ batch, const float* __restrict__ kvec,
        const float* __restrict__ W1, const float* __restrict__ b1,
        const float* __restrict__ W2, const float* __restrict__ b2,
        const float* __restrict__ W3, const float* __restrict__ b3,
        float2* __restrict__ t2) {
    int b  = blockIdx.x >> 4;          // / 16
    int kt = blockIdx.x & 15;
    int d  = threadIdx.x & (D_PET - 1);
    int kg = threadIdx.x >> 7;         // 0/1
    int bk0 = b * NK + kt * SKB;

    __shared__ float  kv_s[SKB * 3];
    __shared__ float  x_lds[D_PET * 18];      // [e][j], row pad 18 -> 9 KB
    __shared__ float  h_lds[32 * D_PET];      // 16 KB
    __shared__ float2 e_lds[32][SKB];         // 4 KB

    if (threadIdx.x < SKB * 3) kv_s[threadIdx.x] = kvec[bk0 * 3 + threadIdx.x];
    __syncthreads();

    // ---- layer 1: 3 -> 128, silu ----
    float w10 = W1[d], w11 = W1[D_PET + d], w12 = W1[2 * D_PET + d];
    float bb1 = b1[d];
#pragma unroll
    for (int i = 0; i < 8; i++) {
        int j = kg * 8 + i;
        float a = fmaf(kv_s[j * 3 + 0], w10,
                  fmaf(kv_s[j * 3 + 1], w11,
                  fmaf(kv_s[j * 3 + 2], w12, bb1)));
        x_lds[d * 18 + j] = silu(a);
    }
    __syncthreads();

    // ---- layer 2: 128 -> 128, silu ----
    float acc[8];
    {
        float bb2 = b2[d];
#pragma unroll
        for (int i = 0; i < 8; i++) acc[i] = bb2;
    }
#pragma unroll 4
    for (int e = 0; e < D_PET; e++) {
        float w = W2[e * D_PET + d];
        float4 xa = *(const float4*)&x_lds[e * 18 + kg * 8];
        float4 xb = *(const float4*)&x_lds[e * 18 + kg * 8 + 4];
        acc[0] = fmaf(xa.x, w, acc[0]); acc[1] = fmaf(xa.y, w, acc[1]);
        acc[2] = fmaf(xa.z, w, acc[2]); acc[3] = fmaf(xa.w, w, acc[3]);
        acc[4] = fmaf(xb.x, w, acc[4]); acc[5] = fmaf(xb.y, w, acc[5]);
        acc[6] = fmaf(xb.z, w, acc[6]); acc[7] = fmaf(xb.w, w, acc[7]);
    }
    __syncthreads();   // all x_lds reads done
#pragma unroll
    for (int i = 0; i < 8; i++) x_lds[d * 18 + kg * 8 + i] = silu(acc[i]);
    __syncthreads();

    // ---- layer 3: 128 -> 128 -> filt in registers ----
    float f[8];
    {
        float bb3 = b3[d];
#pragma unroll
        for (int i = 0; i < 8; i++) f[i] = bb3;
    }
#pragma unroll 4
    for (int e = 0; e < D_PET; e++) {
        float w = W3[e * D_PET + d];
        float4 xa = *(const float4*)&x_lds[e * 18 + kg * 8];
        float4 xb = *(const float4*)&x_lds[e * 18 + kg * 8 + 4];
        f[0] = fmaf(xa.x, w, f[0]); f[1] = fmaf(xa.y, w, f[1]);
        f[2] = fmaf(xa.z, w, f[2]); f[3] = fmaf(xa.w, w, f[3]);
        f[4] = fmaf(xb.x, w, f[4]); f[5] = fmaf(xb.y, w, f[5]);
        f[6] = fmaf(xb.z, w, f[6]); f[7] = fmaf(xb.w, w, f[7]);
    }

    // ---- segment-sum GEMM over this batch's atoms, tiled by 32 ----
    int lo = lower_bound_dev(batch, NB, b);
    int hi = lower_bound_dev(batch, NB, b + 1);

    float sre[8], sim[8];
#pragma unroll
    for (int i = 0; i < 8; i++) { sre[i] = 0.f; sim[i] = 0.f; }

    const float4* h4  = (const float4*)h;
    const float4* pc4 = (const float4*)pc;

    for (int base = lo; base < hi; base += 32) {
        // prefetch tile into registers (bulk, independent loads)
        float4 rh[4];
#pragma unroll
        for (int j = 0; j < 4; j++) {
            int idx = threadIdx.x + j * 256;
            int nn = base + (idx >> 5);
            int c  = idx & 31;
            nn = nn < NB - 1 ? nn : NB - 1;
            rh[j] = h4[(size_t)nn * 32 + c];
        }
        int n_e = threadIdx.x >> 3;
        int kk  = threadIdx.x & 7;
        float4 rE = make_float4(0.f, 0.f, 0.f, 0.f);
        if (base + n_e < hi)
            rE = pc4[(size_t)(base + n_e) * 128 + kt * 8 + kk];

        __syncthreads();   // previous tile's readers done
#pragma unroll
        for (int j = 0; j < 4; j++) {
            int idx = threadIdx.x + j * 256;
            *(float4*)&h_lds[idx * 4] = rh[j];
        }
        *(float4*)&e_lds[n_e][kk * 2] = rE;
        __syncthreads();

#pragma unroll 8
        for (int n = 0; n < 32; n++) {
            float hv = h_lds[n * D_PET + d];
            float4 ea = *(const float4*)&e_lds[n][kg * 8];      // k0,k1
            float4 eb = *(const float4*)&e_lds[n][kg * 8 + 2];  // k2,k3
            float4 ec = *(const float4*)&e_lds[n][kg * 8 + 4];  // k4,k5
            float4 ed = *(const float4*)&e_lds[n][kg * 8 + 6];  // k6,k7
            sre[0] = fmaf(ea.x, hv, sre[0]); sim[0] = fmaf(-ea.y, hv, sim[0]);
            sre[1] = fmaf(ea.z, hv, sre[1]); sim[1] = fmaf(-ea.w, hv, sim[1]);
            sre[2] = fmaf(eb.x, hv, sre[2]); sim[2] = fmaf(-eb.y, hv, sim[2]);
            sre[3] = fmaf(eb.z, hv, sre[3]); sim[3] = fmaf(-eb.w, hv, sim[3]);
            sre[4] = fmaf(ec.x, hv, sre[4]); sim[4] = fmaf(-ec.y, hv, sim[4]);
            sre[5] = fmaf(ec.z, hv, sre[5]); sim[5] = fmaf(-ec.w, hv, sim[5]);
            sre[6] = fmaf(ed.x, hv, sre[6]); sim[6] = fmaf(-ed.y, hv, sim[6]);
            sre[7] = fmaf(ed.z, hv, sre[7]); sim[7] = fmaf(-ed.w, hv, sim[7]);
        }
    }

#pragma unroll
    for (int i = 0; i < 8; i++) {
        int k = kt * SKB + kg * 8 + i;
        t2[((size_t)b * NK + k) * D_PET + d] =
            make_float2(sre[i] * f[i], sim[i] * f[i]);
    }
}

// ---------------------------------------------------------------------------
// Kernel 3: out = per-batch complex GEMM  E(M_b x 256) * T(256 x 128).
// Block = (batch, 8-atom chunk). 256 blocks, 256 threads.
// thread: d = tid&127, ag = tid>>7 -> 4 atoms => 8 accumulators.
// E (8 atoms x 256 k, 20KB padded) staged once per chunk; T staged in 32-k
// tiles (32KB = 2048 float4, 8 float4/thread) with register prefetch.
// Inner: 512 FMA-instr per tile between barriers. LDS 52KB -> 3 blk/CU.
// ---------------------------------------------------------------------------
#define OAT 8      // atoms per chunk
#define OKT 32     // k per tile
#define ONT (NK / OKT)        // 8 tiles
#define TF4 (OKT * D_PET / 2) // 2048 float4 per tile
#define OCH 16     // chunk stride per batch
__global__ __launch_bounds__(256) void out_kernel(
        const float2* __restrict__ pc, const int* __restrict__ batch,
        const float2* __restrict__ t2, float* __restrict__ out,
        int interleaved) {
    int b  = blockIdx.x >> 4;
    int c0 = blockIdx.x & 15;
    int d  = threadIdx.x & (D_PET - 1);
    int ag = threadIdx.x >> 7;    // 0/1 -> atoms ag*4 .. ag*4+3

    int lo = lower_bound_dev(batch, NB, b);
    int hi = lower_bound_dev(batch, NB, b + 1);
    int sz = hi - lo;

    __shared__ float2 e_lds[NK][10];          // [k][atom], pad 10 -> 20 KB
    __shared__ float2 t_lds[OKT * D_PET];     // 32 KB

    const float4* tg  = (const float4*)(t2 + (size_t)b * NK * D_PET);
    const float4* pc4 = (const float4*)pc;
    float* tl = (float*)t_lds;

    for (int ch = c0; ch * OAT < sz; ch += OCH) {
        int nb = lo + ch * OAT;

        // ---- prefetch E (8 atoms x full k) and T tile 0 into registers ----
        float4 rE[4];
        int ra[4], rk[4];
#pragma unroll
        for (int j = 0; j < 4; j++) {
            int i  = threadIdx.x + j * 256;
            int a  = i >> 7;
            int kk = i & 127;
            int n  = nb + a;
            float4 v = make_float4(0.f, 0.f, 0.f, 0.f);
            if (n < hi) v = pc4[(size_t)n * 128 + kk];
            rE[j] = v; ra[j] = a; rk[j] = kk * 2;
        }
        float4 rT[8];
#pragma unroll
        for (int j = 0; j < 8; j++) rT[j] = tg[threadIdx.x + j * 256];

        __syncthreads();   // previous chunk's readers done
#pragma unroll
        for (int j = 0; j < 4; j++) {
            e_lds[rk[j]][ra[j]]     = make_float2(rE[j].x, rE[j].y);
            e_lds[rk[j] + 1][ra[j]] = make_float2(rE[j].z, rE[j].w);
        }
#pragma unroll
        for (int j = 0; j < 8; j++)
            *(float4*)&tl[(threadIdx.x + j * 256) * 4] = rT[j];
        __syncthreads();

        float ore[4] = {0.f, 0.f, 0.f, 0.f};
        float oim[4] = {0.f, 0.f, 0.f, 0.f};

        for (int kt = 0; kt < ONT; kt++) {
            if (kt + 1 < ONT) {
#pragma unroll
                for (int j = 0; j < 8; j++)
                    rT[j] = tg[(size_t)(kt + 1) * TF4 + threadIdx.x + j * 256];
            }
#pragma unroll 8
            for (int kk = 0; kk < OKT; kk++) {
                int k = kt * OKT + kk;
                float2 tv  = t_lds[kk * D_PET + d];
                float4 p01 = *(const float4*)&e_lds[k][ag * 4];
                float4 p23 = *(const float4*)&e_lds[k][ag * 4 + 2];
                ore[0] = fmaf(p01.x, tv.x, ore[0]); ore[0] = fmaf(-p01.y, tv.y, ore[0]);
                oim[0] = fmaf(p01.x, tv.y, oim[0]); oim[0] = fmaf(p01.y, tv.x, oim[0]);
                ore[1] = fmaf(p01.z, tv.x, ore[1]); ore[1] = fmaf(-p01.w, tv.y, ore[1]);
                oim[1] = fmaf(p01.z, tv.y, oim[1]); oim[1] = fmaf(p01.w, tv.x, oim[1]);
                ore[2] = fmaf(p23.x, tv.x, ore[2]); ore[2] = fmaf(-p23.y, tv.y, ore[2]);
                oim[2] = fmaf(p23.x, tv.y, oim[2]); oim[2] = fmaf(p23.y, tv.x, oim[2]);
                ore[3] = fmaf(p23.z, tv.x, ore[3]); ore[3] = fmaf(-p23.w, tv.y, ore[3]);
                oim[3] = fmaf(p23.z, tv.y, oim[3]); oim[3] = fmaf(p23.w, tv.x, oim[3]);
            }
            __syncthreads();   // all reads of t_lds done
            if (kt + 1 < ONT) {
#pragma unroll
                for (int j = 0; j < 8; j++)
                    *(float4*)&tl[(threadIdx.x + j * 256) * 4] = rT[j];
                __syncthreads();   // new tile visible
            }
        }

#pragma unroll
        for (int j = 0; j < 4; j++) {
            int n = nb + ag * 4 + j;
            if (n < hi) {
                if (interleaved) {
                    ((float2*)out)[(size_t)n * D_PET + d] = make_float2(ore[j], oim[j]);
                } else {
                    out[(size_t)n * D_PET + d] = ore[j];
                }
            }
        }
    }
}

// ---------------------------------------------------------------------------
extern "C" void kernel_launch(void* const* d_in, const int* in_sizes, int n_in,
                              void* d_out, int out_size, void* d_ws, size_t ws_size,
                              hipStream_t stream) {
    const float* kvec = (const float*)d_in[0];   // [16,256,3]
    const float* pos  = (const float*)d_in[1];   // [2048,3]
    const float* h    = (const float*)d_in[2];   // [2048,128]
    const float* W1   = (const float*)d_in[3];
    const float* b1   = (const float*)d_in[4];
    const float* W2   = (const float*)d_in[5];
    const float* b2   = (const float*)d_in[6];
    const float* W3   = (const float*)d_in[7];
    const float* b3   = (const float*)d_in[8];
    const int*   batch = (const int*)d_in[9];    // [2048]

    float2* pc = (float2*)d_ws;                              // [NB][NK]    4 MB
    float2* t2 = pc + (size_t)NB * NK;                       // [B][NK][D]  4 MB

    int interleaved = (out_size == NB * D_PET * 2) ? 1 : 0;

    phase_kernel<<<NB, NK, 0, stream>>>(kvec, pos, batch, pc);
    s_fused_kernel<<<NBATCH * 16, 256, 0, stream>>>(h, pc, batch, kvec,
                                                    W1, b1, W2, b2, W3, b3, t2);
    out_kernel<<<NBATCH * 16, 256, 0, stream>>>(pc, batch, t2,
                                                (float*)d_out, interleaved);
}